// Round 1
// baseline (5624.692 us; speedup 1.0000x reference)
//
#include <hip/hip_runtime.h>
#include <hip/hip_bf16.h>

// ---------------------------------------------------------------------------
// TwoLayerGCN: h1 = relu(A@(x@W1)+b1); h2 = relu(A@(h1@W2)+b2);
// g = segsum(h2, seg); g = relu(g@Wd+bd); out = g@Wo+bo
// N=50000 nodes, E=800000 edges, F_IN=128, H=256, G=128 graphs.
// Round 1: correct fp32 baseline. SpMM = atomic scatter (one wave/edge).
// ---------------------------------------------------------------------------

#define BM 64
#define BN 64
#define BK 16

__global__ __launch_bounds__(256) void sgemm(
    const float* __restrict__ A, const float* __restrict__ B,
    float* __restrict__ C, int M, int N, int K)
{
    // C[M,N] = A[M,K] @ B[K,N], all row-major. 64x64 tile, 4x4 per thread.
    __shared__ float As[BK][BM + 1];   // As[k][m], +1 pad: conflict-free stores
    __shared__ float Bs[BK][BN];       // Bs[k][n]

    const int tid = threadIdx.x;
    const int tx = tid & 15;           // n-tile coord
    const int ty = tid >> 4;           // m-tile coord
    const int bm = blockIdx.x * BM;
    const int bn = blockIdx.y * BN;

    // A-load mapping: 64 rows x 16 k; 4 threads/row, float4 each
    const int arow = tid >> 2;
    const int acol = (tid & 3) * 4;
    // B-load mapping: 16 k-rows x 64 n; 16 threads/row, float4 each
    const int brow = tid >> 4;
    const int bcol = (tid & 15) * 4;

    float acc[4][4] = {};

    for (int k0 = 0; k0 < K; k0 += BK) {
        float4 av = make_float4(0.f, 0.f, 0.f, 0.f);
        if (bm + arow < M)
            av = *(const float4*)(A + (size_t)(bm + arow) * K + k0 + acol);
        As[acol + 0][arow] = av.x;
        As[acol + 1][arow] = av.y;
        As[acol + 2][arow] = av.z;
        As[acol + 3][arow] = av.w;

        float4 bv = *(const float4*)(B + (size_t)(k0 + brow) * N + bn + bcol);
        *(float4*)&Bs[brow][bcol] = bv;
        __syncthreads();

        #pragma unroll
        for (int k = 0; k < BK; k++) {
            float a[4], b[4];
            #pragma unroll
            for (int i = 0; i < 4; i++) a[i] = As[k][ty * 4 + i];
            #pragma unroll
            for (int j = 0; j < 4; j++) b[j] = Bs[k][tx * 4 + j];
            #pragma unroll
            for (int i = 0; i < 4; i++)
                #pragma unroll
                for (int j = 0; j < 4; j++)
                    acc[i][j] += a[i] * b[j];
        }
        __syncthreads();
    }

    #pragma unroll
    for (int i = 0; i < 4; i++) {
        int row = bm + ty * 4 + i;
        if (row < M) {
            float4 v = make_float4(acc[i][0], acc[i][1], acc[i][2], acc[i][3]);
            *(float4*)(C + (size_t)row * N + bn + tx * 4) = v;
        }
    }
}

// One 64-lane wave per edge; lane l handles features 4l..4l+3 (256 total).
__global__ __launch_bounds__(256) void spmm_scatter(
    const float* __restrict__ H, const int* __restrict__ src,
    const int* __restrict__ dst, const float* __restrict__ w,
    float* __restrict__ out, int E)
{
    int edge = blockIdx.x * 4 + (threadIdx.x >> 6);
    if (edge >= E) return;
    int lane = threadIdx.x & 63;
    int s = src[edge];
    int d = dst[edge];
    float wt = w[edge];
    float4 v = *(const float4*)(H + (size_t)s * 256 + lane * 4);
    float* orow = out + (size_t)d * 256 + lane * 4;
    atomicAdd(orow + 0, v.x * wt);
    atomicAdd(orow + 1, v.y * wt);
    atomicAdd(orow + 2, v.z * wt);
    atomicAdd(orow + 3, v.w * wt);
}

__global__ __launch_bounds__(256) void bias_relu(
    float* __restrict__ h, const float* __restrict__ b, int n_nodes)
{
    size_t idx = (size_t)blockIdx.x * 256 + threadIdx.x;  // one float4 each
    if (idx >= (size_t)n_nodes * 64) return;
    int f4 = idx & 63;
    float4 v = ((float4*)h)[idx];
    float4 bb = ((const float4*)b)[f4];
    v.x = fmaxf(v.x + bb.x, 0.f);
    v.y = fmaxf(v.y + bb.y, 0.f);
    v.z = fmaxf(v.z + bb.z, 0.f);
    v.w = fmaxf(v.w + bb.w, 0.f);
    ((float4*)h)[idx] = v;
}

// Block = 256 threads (one/feature), chunk of 128 consecutive nodes.
// Register-accumulate while segment id unchanged; atomic flush on change.
__global__ __launch_bounds__(256) void pool_seg(
    const float* __restrict__ h, const int* __restrict__ seg,
    float* __restrict__ g, int n_nodes)
{
    int f = threadIdx.x;
    int n0 = blockIdx.x * 128;
    int n1 = min(n0 + 128, n_nodes);
    float acc = 0.f;
    int cur = seg[n0];
    for (int n = n0; n < n1; n++) {
        int s = seg[n];
        if (s != cur) {
            atomicAdd(&g[(size_t)cur * 256 + f], acc);
            acc = 0.f;
            cur = s;
        }
        acc += h[(size_t)n * 256 + f];
    }
    atomicAdd(&g[(size_t)cur * 256 + f], acc);
}

__global__ __launch_bounds__(256) void head_dense(
    const float* __restrict__ g, const float* __restrict__ Wd,
    const float* __restrict__ bd, float* __restrict__ g2)
{
    __shared__ float gr[256];
    int j = threadIdx.x;
    int gi = blockIdx.x;
    gr[j] = g[(size_t)gi * 256 + j];
    __syncthreads();
    float acc = bd[j];
    for (int k = 0; k < 256; k++)
        acc += gr[k] * Wd[(size_t)k * 256 + j];
    g2[(size_t)gi * 256 + j] = fmaxf(acc, 0.f);
}

__global__ __launch_bounds__(256) void head_out(
    const float* __restrict__ g2, const float* __restrict__ Wo,
    const float* __restrict__ bo, float* __restrict__ out)
{
    int j = threadIdx.x;
    int gi = blockIdx.x;
    float v = g2[(size_t)gi * 256 + j] * Wo[j];
    #pragma unroll
    for (int off = 32; off > 0; off >>= 1)
        v += __shfl_down(v, off, 64);
    __shared__ float partial[4];
    if ((j & 63) == 0) partial[j >> 6] = v;
    __syncthreads();
    if (j == 0)
        out[gi] = partial[0] + partial[1] + partial[2] + partial[3] + bo[0];
}

extern "C" void kernel_launch(void* const* d_in, const int* in_sizes, int n_in,
                              void* d_out, int out_size, void* d_ws, size_t ws_size,
                              hipStream_t stream) {
    const float* x   = (const float*)d_in[0];
    const int*   esrc= (const int*)  d_in[1];
    const int*   edst= (const int*)  d_in[2];
    const float* ew  = (const float*)d_in[3];
    const int*   seg = (const int*)  d_in[4];
    const float* W1  = (const float*)d_in[5];
    const float* b1  = (const float*)d_in[6];
    const float* W2  = (const float*)d_in[7];
    const float* b2  = (const float*)d_in[8];
    const float* Wd  = (const float*)d_in[9];
    const float* bd  = (const float*)d_in[10];
    const float* Wo  = (const float*)d_in[11];
    const float* bo  = (const float*)d_in[12];
    float* out = (float*)d_out;

    const int N = 50000, E = 800000, G = 128, H = 256;

    float* bufA = (float*)d_ws;                    // [N,256] GEMM out
    float* bufB = bufA + (size_t)N * H;            // [N,256] SpMM out
    float* g    = bufB + (size_t)N * H;            // [G,256]
    float* g2   = g + (size_t)G * H;               // [G,256]

    // h1 path
    sgemm<<<dim3((N + BM - 1) / BM, H / BN), 256, 0, stream>>>(x, W1, bufA, N, H, 128);
    hipMemsetAsync(bufB, 0, (size_t)N * H * sizeof(float), stream);
    spmm_scatter<<<(E + 3) / 4, 256, 0, stream>>>(bufA, esrc, edst, ew, bufB, E);
    bias_relu<<<(N * 64 + 255) / 256, 256, 0, stream>>>(bufB, b1, N);

    // h2 path
    sgemm<<<dim3((N + BM - 1) / BM, H / BN), 256, 0, stream>>>(bufB, W2, bufA, N, H, H);
    hipMemsetAsync(bufB, 0, (size_t)N * H * sizeof(float), stream);
    spmm_scatter<<<(E + 3) / 4, 256, 0, stream>>>(bufA, esrc, edst, ew, bufB, E);
    bias_relu<<<(N * 64 + 255) / 256, 256, 0, stream>>>(bufB, b2, N);

    // pool + head
    hipMemsetAsync(g, 0, (size_t)G * H * sizeof(float), stream);
    pool_seg<<<(N + 127) / 128, 256, 0, stream>>>(bufB, seg, g, N);
    head_dense<<<G, 256, 0, stream>>>(g, Wd, bd, g2);
    head_out<<<G, 256, 0, stream>>>(g2, Wo, bo, out);
}

// Round 2
// 606.468 us; speedup vs baseline: 9.2745x; 9.2745x over previous
//
#include <hip/hip_runtime.h>
#include <hip/hip_bf16.h>

// ---------------------------------------------------------------------------
// TwoLayerGCN: h1 = relu(A@(x@W1)+b1); h2 = relu(A@(h1@W2)+b2);
// g = segsum(h2, seg); g = relu(g@Wd+bd); out = g@Wo+bo
// N=50000 nodes, E=800000 edges, F_IN=128, H=256, G=128 graphs.
// Round 2: SpMM scatter -> CSR gather. R1 counters: spmm_scatter wrote
// 3.2 GB/dispatch (atomics, 62x overwrite), 2x2650us of 5625us total.
// Gather writes each output row exactly once; bias+relu fused in epilogue.
// ---------------------------------------------------------------------------

#define BM 64
#define BN 64
#define BK 16

__global__ __launch_bounds__(256) void sgemm(
    const float* __restrict__ A, const float* __restrict__ B,
    float* __restrict__ C, int M, int N, int K)
{
    // C[M,N] = A[M,K] @ B[K,N], all row-major. 64x64 tile, 4x4 per thread.
    __shared__ float As[BK][BM + 1];
    __shared__ float Bs[BK][BN];

    const int tid = threadIdx.x;
    const int tx = tid & 15;
    const int ty = tid >> 4;
    const int bm = blockIdx.x * BM;
    const int bn = blockIdx.y * BN;

    const int arow = tid >> 2;
    const int acol = (tid & 3) * 4;
    const int brow = tid >> 4;
    const int bcol = (tid & 15) * 4;

    float acc[4][4] = {};

    for (int k0 = 0; k0 < K; k0 += BK) {
        float4 av = make_float4(0.f, 0.f, 0.f, 0.f);
        if (bm + arow < M)
            av = *(const float4*)(A + (size_t)(bm + arow) * K + k0 + acol);
        As[acol + 0][arow] = av.x;
        As[acol + 1][arow] = av.y;
        As[acol + 2][arow] = av.z;
        As[acol + 3][arow] = av.w;

        float4 bv = *(const float4*)(B + (size_t)(k0 + brow) * N + bn + bcol);
        *(float4*)&Bs[brow][bcol] = bv;
        __syncthreads();

        #pragma unroll
        for (int k = 0; k < BK; k++) {
            float a[4], b[4];
            #pragma unroll
            for (int i = 0; i < 4; i++) a[i] = As[k][ty * 4 + i];
            #pragma unroll
            for (int j = 0; j < 4; j++) b[j] = Bs[k][tx * 4 + j];
            #pragma unroll
            for (int i = 0; i < 4; i++)
                #pragma unroll
                for (int j = 0; j < 4; j++)
                    acc[i][j] += a[i] * b[j];
        }
        __syncthreads();
    }

    #pragma unroll
    for (int i = 0; i < 4; i++) {
        int row = bm + ty * 4 + i;
        if (row < M) {
            float4 v = make_float4(acc[i][0], acc[i][1], acc[i][2], acc[i][3]);
            *(float4*)(C + (size_t)row * N + bn + tx * 4) = v;
        }
    }
}

// ---------------- CSR-by-destination build (once per launch) ----------------

__global__ __launch_bounds__(256) void csr_hist(
    const int* __restrict__ dst, int* __restrict__ deg, int E)
{
    int e = blockIdx.x * 256 + threadIdx.x;
    if (e < E) atomicAdd(&deg[dst[e]], 1);
}

// Per-block Hillis-Steele scan of 256 elems; writes exclusive prefix + block sum.
__global__ __launch_bounds__(256) void scan_block(
    const int* __restrict__ deg, int* __restrict__ off,
    int* __restrict__ blocksums, int n)
{
    __shared__ int s[256];
    int tid = threadIdx.x;
    int gid = blockIdx.x * 256 + tid;
    int v = (gid < n) ? deg[gid] : 0;
    s[tid] = v;
    __syncthreads();
    for (int o = 1; o < 256; o <<= 1) {
        int t = (tid >= o) ? s[tid - o] : 0;
        __syncthreads();
        s[tid] += t;
        __syncthreads();
    }
    if (gid < n) off[gid] = s[tid] - v;       // exclusive
    if (tid == 255) blocksums[blockIdx.x] = s[255];
}

__global__ __launch_bounds__(256) void scan_top(
    const int* __restrict__ blocksums, int* __restrict__ blockoffs, int nb)
{
    __shared__ int s[256];
    int tid = threadIdx.x;
    int v = (tid < nb) ? blocksums[tid] : 0;
    s[tid] = v;
    __syncthreads();
    for (int o = 1; o < 256; o <<= 1) {
        int t = (tid >= o) ? s[tid - o] : 0;
        __syncthreads();
        s[tid] += t;
        __syncthreads();
    }
    if (tid < nb) blockoffs[tid] = s[tid] - v;
}

__global__ __launch_bounds__(256) void scan_apply(
    int* __restrict__ off, const int* __restrict__ blockoffs,
    int* __restrict__ cursor, int n, int E)
{
    int gid = blockIdx.x * 256 + threadIdx.x;
    if (gid < n) {
        int v = off[gid] + blockoffs[gid >> 8];
        off[gid] = v;
        cursor[gid] = v;
    }
    if (gid == 0) off[n] = E;
}

__global__ __launch_bounds__(256) void csr_fill(
    const int* __restrict__ src, const int* __restrict__ dst,
    const float* __restrict__ w, int* __restrict__ cursor,
    int* __restrict__ srcs_s, float* __restrict__ ws_s, int E)
{
    int e = blockIdx.x * 256 + threadIdx.x;
    if (e >= E) return;
    int d = dst[e];
    int p = atomicAdd(&cursor[d], 1);
    srcs_s[p] = src[e];
    ws_s[p] = w[e];
}

// ------------------------- gather SpMM + bias + relu ------------------------
// One 64-lane wave per destination node; lane l owns features 4l..4l+3.
__global__ __launch_bounds__(256) void spmm_gather(
    const float* __restrict__ Hin, const int* __restrict__ off,
    const int* __restrict__ srcs, const float* __restrict__ ew,
    const float* __restrict__ bias, float* __restrict__ out, int n)
{
    int node = blockIdx.x * 4 + (threadIdx.x >> 6);
    if (node >= n) return;
    int lane = threadIdx.x & 63;
    int e0 = off[node], e1 = off[node + 1];
    float ax = 0.f, ay = 0.f, az = 0.f, aw = 0.f;
    int e = e0;
    for (; e + 2 <= e1; e += 2) {
        int s0 = srcs[e], s1 = srcs[e + 1];
        float w0 = ew[e], w1 = ew[e + 1];
        float4 v0 = *(const float4*)(Hin + (size_t)s0 * 256 + lane * 4);
        float4 v1 = *(const float4*)(Hin + (size_t)s1 * 256 + lane * 4);
        ax += v0.x * w0; ay += v0.y * w0; az += v0.z * w0; aw += v0.w * w0;
        ax += v1.x * w1; ay += v1.y * w1; az += v1.z * w1; aw += v1.w * w1;
    }
    if (e < e1) {
        int s0 = srcs[e];
        float w0 = ew[e];
        float4 v0 = *(const float4*)(Hin + (size_t)s0 * 256 + lane * 4);
        ax += v0.x * w0; ay += v0.y * w0; az += v0.z * w0; aw += v0.w * w0;
    }
    float4 bb = ((const float4*)bias)[lane];
    float4 o;
    o.x = fmaxf(ax + bb.x, 0.f);
    o.y = fmaxf(ay + bb.y, 0.f);
    o.z = fmaxf(az + bb.z, 0.f);
    o.w = fmaxf(aw + bb.w, 0.f);
    *(float4*)(out + (size_t)node * 256 + lane * 4) = o;
}

// ------------------------------- pool + head --------------------------------

__global__ __launch_bounds__(256) void pool_seg(
    const float* __restrict__ h, const int* __restrict__ seg,
    float* __restrict__ g, int n_nodes)
{
    int f = threadIdx.x;
    int n0 = blockIdx.x * 128;
    int n1 = min(n0 + 128, n_nodes);
    float acc = 0.f;
    int cur = seg[n0];
    for (int n = n0; n < n1; n++) {
        int s = seg[n];
        if (s != cur) {
            atomicAdd(&g[(size_t)cur * 256 + f], acc);
            acc = 0.f;
            cur = s;
        }
        acc += h[(size_t)n * 256 + f];
    }
    atomicAdd(&g[(size_t)cur * 256 + f], acc);
}

__global__ __launch_bounds__(256) void head_dense(
    const float* __restrict__ g, const float* __restrict__ Wd,
    const float* __restrict__ bd, float* __restrict__ g2)
{
    __shared__ float gr[256];
    int j = threadIdx.x;
    int gi = blockIdx.x;
    gr[j] = g[(size_t)gi * 256 + j];
    __syncthreads();
    float acc = bd[j];
    for (int k = 0; k < 256; k++)
        acc += gr[k] * Wd[(size_t)k * 256 + j];
    g2[(size_t)gi * 256 + j] = fmaxf(acc, 0.f);
}

__global__ __launch_bounds__(256) void head_out(
    const float* __restrict__ g2, const float* __restrict__ Wo,
    const float* __restrict__ bo, float* __restrict__ out)
{
    int j = threadIdx.x;
    int gi = blockIdx.x;
    float v = g2[(size_t)gi * 256 + j] * Wo[j];
    #pragma unroll
    for (int off = 32; off > 0; off >>= 1)
        v += __shfl_down(v, off, 64);
    __shared__ float partial[4];
    if ((j & 63) == 0) partial[j >> 6] = v;
    __syncthreads();
    if (j == 0)
        out[gi] = partial[0] + partial[1] + partial[2] + partial[3] + bo[0];
}

extern "C" void kernel_launch(void* const* d_in, const int* in_sizes, int n_in,
                              void* d_out, int out_size, void* d_ws, size_t ws_size,
                              hipStream_t stream) {
    const float* x   = (const float*)d_in[0];
    const int*   esrc= (const int*)  d_in[1];
    const int*   edst= (const int*)  d_in[2];
    const float* ew  = (const float*)d_in[3];
    const int*   seg = (const int*)  d_in[4];
    const float* W1  = (const float*)d_in[5];
    const float* b1  = (const float*)d_in[6];
    const float* W2  = (const float*)d_in[7];
    const float* b2  = (const float*)d_in[8];
    const float* Wd  = (const float*)d_in[9];
    const float* bd  = (const float*)d_in[10];
    const float* Wo  = (const float*)d_in[11];
    const float* bo  = (const float*)d_in[12];
    float* out = (float*)d_out;

    const int N = 50000, E = 800000, G = 128, H = 256;
    const int NB = (N + 255) / 256;   // 196 scan blocks

    char* p = (char*)d_ws;
    float* bufA = (float*)p;            p += (size_t)N * H * sizeof(float);
    float* bufB = (float*)p;            p += (size_t)N * H * sizeof(float);
    float* g    = (float*)p;            p += (size_t)G * H * sizeof(float);
    float* g2   = (float*)p;            p += (size_t)G * H * sizeof(float);
    int*   deg  = (int*)p;              p += (size_t)N * sizeof(int);
    int*   off  = (int*)p;              p += (size_t)(N + 1) * sizeof(int);
    int*   cur  = (int*)p;              p += (size_t)N * sizeof(int);
    int*   bsum = (int*)p;              p += 256 * sizeof(int);
    int*   boff = (int*)p;              p += 256 * sizeof(int);
    int*   srcs = (int*)p;              p += (size_t)E * sizeof(int);
    float* ews  = (float*)p;            p += (size_t)E * sizeof(float);

    // ---- CSR build (same graph for both layers) ----
    hipMemsetAsync(deg, 0, (size_t)N * sizeof(int), stream);
    csr_hist<<<(E + 255) / 256, 256, 0, stream>>>(edst, deg, E);
    scan_block<<<NB, 256, 0, stream>>>(deg, off, bsum, N);
    scan_top<<<1, 256, 0, stream>>>(bsum, boff, NB);
    scan_apply<<<NB, 256, 0, stream>>>(off, boff, cur, N, E);
    csr_fill<<<(E + 255) / 256, 256, 0, stream>>>(esrc, edst, ew, cur, srcs, ews, E);

    // ---- layer 1 ----
    sgemm<<<dim3((N + BM - 1) / BM, H / BN), 256, 0, stream>>>(x, W1, bufA, N, H, 128);
    spmm_gather<<<(N + 3) / 4, 256, 0, stream>>>(bufA, off, srcs, ews, b1, bufB, N);

    // ---- layer 2 ----
    sgemm<<<dim3((N + BM - 1) / BM, H / BN), 256, 0, stream>>>(bufB, W2, bufA, N, H, H);
    spmm_gather<<<(N + 3) / 4, 256, 0, stream>>>(bufA, off, srcs, ews, b2, bufB, N);

    // ---- pool + head ----
    hipMemsetAsync(g, 0, (size_t)G * H * sizeof(float), stream);
    pool_seg<<<(N + 127) / 128, 256, 0, stream>>>(bufB, seg, g, N);
    head_dense<<<G, 256, 0, stream>>>(g, Wd, bd, g2);
    head_out<<<G, 256, 0, stream>>>(g2, Wo, bo, out);
}

// Round 3
// 477.688 us; speedup vs baseline: 11.7748x; 1.2696x over previous
//
#include <hip/hip_runtime.h>
#include <hip/hip_bf16.h>

// ---------------------------------------------------------------------------
// TwoLayerGCN. Round 3:
//  - reorder: spmm(x@W) == spmm(x)@W  -> gather the NARROW side first
//  - gather operands stored bf16 (rows 256B/512B, working set 12.8/25.6 MB)
//  - GEMMs on MFMA bf16 (16x16x32), bias+relu fused, Wt pre-transposed [N,K]
// R2 counters: spmm fetch-bound (376 MB @ 3.85 TB/s, 1 KB random rows).
// ---------------------------------------------------------------------------

typedef short v8s __attribute__((ext_vector_type(8)));
typedef float v4f __attribute__((ext_vector_type(4)));

__device__ inline unsigned bf16u(float f) {           // fp32 -> bf16 bits (RNE)
    unsigned u = __builtin_bit_cast(unsigned, f);
    return (u + 0x7fffu + ((u >> 16) & 1u)) >> 16;
}
__device__ inline float bflo(unsigned v) { return __builtin_bit_cast(float, v << 16); }
__device__ inline float bfhi(unsigned v) { return __builtin_bit_cast(float, v & 0xffff0000u); }

// ----------------------------- conversions ---------------------------------

__global__ __launch_bounds__(256) void to_bf16_4(
    const float* __restrict__ in, ushort* __restrict__ out, int n4)
{
    int i = blockIdx.x * 256 + threadIdx.x;
    if (i >= n4) return;
    float4 v = ((const float4*)in)[i];
    unsigned lo = (bf16u(v.y) << 16) | bf16u(v.x);
    unsigned hi = (bf16u(v.w) << 16) | bf16u(v.z);
    ((uint2*)out)[i] = make_uint2(lo, hi);
}

// Wt[n*K+k] = bf16(W[k*N+n]); grid = N blocks, block = K threads
__global__ void wtrans(const float* __restrict__ W, ushort* __restrict__ Wt,
                       int K, int N)
{
    int n = blockIdx.x, k = threadIdx.x;
    Wt[n * K + k] = (ushort)bf16u(W[k * N + n]);
}

// ---------------- CSR-by-destination build (once per launch) ----------------

__global__ __launch_bounds__(256) void csr_hist(
    const int* __restrict__ dst, int* __restrict__ deg, int E)
{
    int e = blockIdx.x * 256 + threadIdx.x;
    if (e < E) atomicAdd(&deg[dst[e]], 1);
}

__global__ __launch_bounds__(256) void scan_block(
    const int* __restrict__ deg, int* __restrict__ off,
    int* __restrict__ blocksums, int n)
{
    __shared__ int s[256];
    int tid = threadIdx.x;
    int gid = blockIdx.x * 256 + tid;
    int v = (gid < n) ? deg[gid] : 0;
    s[tid] = v;
    __syncthreads();
    for (int o = 1; o < 256; o <<= 1) {
        int t = (tid >= o) ? s[tid - o] : 0;
        __syncthreads();
        s[tid] += t;
        __syncthreads();
    }
    if (gid < n) off[gid] = s[tid] - v;
    if (tid == 255) blocksums[blockIdx.x] = s[255];
}

__global__ __launch_bounds__(256) void scan_top(
    const int* __restrict__ blocksums, int* __restrict__ blockoffs, int nb)
{
    __shared__ int s[256];
    int tid = threadIdx.x;
    int v = (tid < nb) ? blocksums[tid] : 0;
    s[tid] = v;
    __syncthreads();
    for (int o = 1; o < 256; o <<= 1) {
        int t = (tid >= o) ? s[tid - o] : 0;
        __syncthreads();
        s[tid] += t;
        __syncthreads();
    }
    if (tid < nb) blockoffs[tid] = s[tid] - v;
}

__global__ __launch_bounds__(256) void scan_apply(
    int* __restrict__ off, const int* __restrict__ blockoffs,
    int* __restrict__ cursor, int n, int E)
{
    int gid = blockIdx.x * 256 + threadIdx.x;
    if (gid < n) {
        int v = off[gid] + blockoffs[gid >> 8];
        off[gid] = v;
        cursor[gid] = v;
    }
    if (gid == 0) off[n] = E;
}

__global__ __launch_bounds__(256) void csr_fill(
    const int* __restrict__ src, const int* __restrict__ dst,
    const float* __restrict__ w, int* __restrict__ cursor,
    int* __restrict__ srcs_s, float* __restrict__ ws_s, int E)
{
    int e = blockIdx.x * 256 + threadIdx.x;
    if (e >= E) return;
    int d = dst[e];
    int p = atomicAdd(&cursor[d], 1);
    srcs_s[p] = src[e];
    ws_s[p] = w[e];
}

// ----------------------- gather SpMM (bf16 in/out) --------------------------
// 128 feats: lane owns feats {2l, 2l+1} (one uint = 2 bf16), fp32 accum.
__global__ __launch_bounds__(256) void spmm128(
    const ushort* __restrict__ xh, const int* __restrict__ off,
    const int* __restrict__ srcs, const float* __restrict__ ew,
    ushort* __restrict__ S, int n)
{
    int node = blockIdx.x * 4 + (threadIdx.x >> 6);
    if (node >= n) return;
    int lane = threadIdx.x & 63;
    const unsigned* base = (const unsigned*)xh;   // row stride 64 uints
    int e0 = off[node], e1 = off[node + 1];
    float a0 = 0.f, a1 = 0.f;
    int e = e0;
    for (; e + 2 <= e1; e += 2) {
        int s0 = srcs[e], s1 = srcs[e + 1];
        float w0 = ew[e], w1 = ew[e + 1];
        unsigned v0 = base[(size_t)s0 * 64 + lane];
        unsigned v1 = base[(size_t)s1 * 64 + lane];
        a0 += bflo(v0) * w0 + bflo(v1) * w1;
        a1 += bfhi(v0) * w0 + bfhi(v1) * w1;
    }
    if (e < e1) {
        int s0 = srcs[e];
        float w0 = ew[e];
        unsigned v0 = base[(size_t)s0 * 64 + lane];
        a0 += bflo(v0) * w0;
        a1 += bfhi(v0) * w0;
    }
    ((unsigned*)S)[(size_t)node * 64 + lane] = (bf16u(a1) << 16) | bf16u(a0);
}

// 256 feats: lane owns feats {4l..4l+3} (uint2 = 4 bf16), fp32 accum.
__global__ __launch_bounds__(256) void spmm256(
    const ushort* __restrict__ hh, const int* __restrict__ off,
    const int* __restrict__ srcs, const float* __restrict__ ew,
    ushort* __restrict__ S, int n)
{
    int node = blockIdx.x * 4 + (threadIdx.x >> 6);
    if (node >= n) return;
    int lane = threadIdx.x & 63;
    const uint2* base = (const uint2*)hh;          // row stride 64 uint2
    int e0 = off[node], e1 = off[node + 1];
    float a0 = 0.f, a1 = 0.f, a2 = 0.f, a3 = 0.f;
    int e = e0;
    for (; e + 2 <= e1; e += 2) {
        int s0 = srcs[e], s1 = srcs[e + 1];
        float w0 = ew[e], w1 = ew[e + 1];
        uint2 v0 = base[(size_t)s0 * 64 + lane];
        uint2 v1 = base[(size_t)s1 * 64 + lane];
        a0 += bflo(v0.x) * w0 + bflo(v1.x) * w1;
        a1 += bfhi(v0.x) * w0 + bfhi(v1.x) * w1;
        a2 += bflo(v0.y) * w0 + bflo(v1.y) * w1;
        a3 += bfhi(v0.y) * w0 + bfhi(v1.y) * w1;
    }
    if (e < e1) {
        int s0 = srcs[e];
        float w0 = ew[e];
        uint2 v0 = base[(size_t)s0 * 64 + lane];
        a0 += bflo(v0.x) * w0;
        a1 += bfhi(v0.x) * w0;
        a2 += bflo(v0.y) * w0;
        a3 += bfhi(v0.y) * w0;
    }
    uint2 o;
    o.x = (bf16u(a1) << 16) | bf16u(a0);
    o.y = (bf16u(a3) << 16) | bf16u(a2);
    ((uint2*)S)[(size_t)node * 64 + lane] = o;
}

// --------------------------- MFMA bf16 GEMM ---------------------------------
// C[M,256] = relu(A[M,K] @ W[K,256] + bias). A bf16 row-major, Wt[N=256,K] bf16.
// One wave per 16-row strip; 16 col-tiles => 16 acc frags (64 VGPRs).
// A-frag: lane(r=l&15,q=l>>4) holds A[r][q*8+j]; B-frag: Wt[ct*16+r][q*8+j];
// D: row=q*4+i, col=r (guide §3, m89/m91-verified mapping).
template <int K, bool BF16OUT>
__global__ __launch_bounds__(256) void gemm_mfma(
    const ushort* __restrict__ A, const ushort* __restrict__ Wt,
    const float* __restrict__ bias, void* __restrict__ out, int M)
{
    int wave = blockIdx.x * 4 + (threadIdx.x >> 6);
    if (wave >= (M >> 4)) return;
    int lane = threadIdx.x & 63;
    int r = lane & 15, q = lane >> 4;

    const v8s* Arow = (const v8s*)(A + (size_t)(wave * 16 + r) * K + q * 8);

    v4f acc[16];
    #pragma unroll
    for (int i = 0; i < 16; i++) acc[i] = (v4f){0.f, 0.f, 0.f, 0.f};

    #pragma unroll
    for (int kk = 0; kk < K / 32; kk++) {
        v8s af = Arow[kk * 4];                     // k = kk*32 + q*8 .. +7
        #pragma unroll
        for (int ct = 0; ct < 16; ct++) {
            v8s bf = *(const v8s*)(Wt + (size_t)(ct * 16 + r) * K + kk * 32 + q * 8);
            acc[ct] = __builtin_amdgcn_mfma_f32_16x16x32_bf16(af, bf, acc[ct], 0, 0, 0);
        }
    }

    #pragma unroll
    for (int ct = 0; ct < 16; ct++) {
        int col = ct * 16 + r;
        float b = bias[col];
        #pragma unroll
        for (int i = 0; i < 4; i++) {
            size_t row = (size_t)wave * 16 + q * 4 + i;
            float v = fmaxf(acc[ct][i] + b, 0.f);
            if constexpr (BF16OUT)
                ((ushort*)out)[row * 256 + col] = (ushort)bf16u(v);
            else
                ((float*)out)[row * 256 + col] = v;
        }
    }
}

// ------------------------------- pool + head --------------------------------

__global__ __launch_bounds__(256) void pool_seg(
    const float* __restrict__ h, const int* __restrict__ seg,
    float* __restrict__ g, int n_nodes)
{
    int f = threadIdx.x;
    int n0 = blockIdx.x * 128;
    int n1 = min(n0 + 128, n_nodes);
    float acc = 0.f;
    int cur = seg[n0];
    for (int n = n0; n < n1; n++) {
        int s = seg[n];
        if (s != cur) {
            atomicAdd(&g[(size_t)cur * 256 + f], acc);
            acc = 0.f;
            cur = s;
        }
        acc += h[(size_t)n * 256 + f];
    }
    atomicAdd(&g[(size_t)cur * 256 + f], acc);
}

__global__ __launch_bounds__(256) void head_dense(
    const float* __restrict__ g, const float* __restrict__ Wd,
    const float* __restrict__ bd, float* __restrict__ g2)
{
    __shared__ float gr[256];
    int j = threadIdx.x;
    int gi = blockIdx.x;
    gr[j] = g[(size_t)gi * 256 + j];
    __syncthreads();
    float acc = bd[j];
    for (int k = 0; k < 256; k++)
        acc += gr[k] * Wd[(size_t)k * 256 + j];
    g2[(size_t)gi * 256 + j] = fmaxf(acc, 0.f);
}

__global__ __launch_bounds__(256) void head_out(
    const float* __restrict__ g2, const float* __restrict__ Wo,
    const float* __restrict__ bo, float* __restrict__ out)
{
    int j = threadIdx.x;
    int gi = blockIdx.x;
    float v = g2[(size_t)gi * 256 + j] * Wo[j];
    #pragma unroll
    for (int off = 32; off > 0; off >>= 1)
        v += __shfl_down(v, off, 64);
    __shared__ float partial[4];
    if ((j & 63) == 0) partial[j >> 6] = v;
    __syncthreads();
    if (j == 0)
        out[gi] = partial[0] + partial[1] + partial[2] + partial[3] + bo[0];
}

extern "C" void kernel_launch(void* const* d_in, const int* in_sizes, int n_in,
                              void* d_out, int out_size, void* d_ws, size_t ws_size,
                              hipStream_t stream) {
    const float* x   = (const float*)d_in[0];
    const int*   esrc= (const int*)  d_in[1];
    const int*   edst= (const int*)  d_in[2];
    const float* ew  = (const float*)d_in[3];
    const int*   seg = (const int*)  d_in[4];
    const float* W1  = (const float*)d_in[5];
    const float* b1  = (const float*)d_in[6];
    const float* W2  = (const float*)d_in[7];
    const float* b2  = (const float*)d_in[8];
    const float* Wd  = (const float*)d_in[9];
    const float* bd  = (const float*)d_in[10];
    const float* Wo  = (const float*)d_in[11];
    const float* bo  = (const float*)d_in[12];
    float* out = (float*)d_out;

    const int N = 50000, E = 800000, G = 128, H = 256, F = 128;
    const int NB = (N + 255) / 256;

    // workspace layout; region0 is reused: {xh, S1} early, h2 (fp32) late
    char* p = (char*)d_ws;
    char* region0 = p;                  p += (size_t)N * H * sizeof(float);   // 51.2 MB
    ushort* xh = (ushort*)region0;                                            // [N,128] bf16
    ushort* S1 = (ushort*)(region0 + (size_t)N * F * sizeof(ushort));         // [N,128] bf16
    float*  h2 = (float*)region0;                                             // [N,256] f32
    ushort* h1 = (ushort*)p;            p += (size_t)N * H * sizeof(ushort);  // [N,256] bf16
    ushort* S2 = (ushort*)p;            p += (size_t)N * H * sizeof(ushort);  // [N,256] bf16
    float* g   = (float*)p;             p += (size_t)G * H * sizeof(float);
    float* g2  = (float*)p;             p += (size_t)G * H * sizeof(float);
    int*   deg = (int*)p;               p += (size_t)N * sizeof(int);
    int*   off = (int*)p;               p += (size_t)(N + 1) * sizeof(int) + 12;
    int*   cur = (int*)p;               p += (size_t)N * sizeof(int);
    int*   bsum= (int*)p;               p += 256 * sizeof(int);
    int*   boff= (int*)p;               p += 256 * sizeof(int);
    int*   srcs= (int*)p;               p += (size_t)E * sizeof(int);
    float* ews = (float*)p;             p += (size_t)E * sizeof(float);
    ushort* Wt1= (ushort*)p;            p += (size_t)H * F * sizeof(ushort);  // [256,128]
    ushort* Wt2= (ushort*)p;            p += (size_t)H * H * sizeof(ushort);  // [256,256]

    // ---- CSR build + weight/feature conversion ----
    hipMemsetAsync(deg, 0, (size_t)N * sizeof(int), stream);
    csr_hist<<<(E + 255) / 256, 256, 0, stream>>>(edst, deg, E);
    scan_block<<<NB, 256, 0, stream>>>(deg, off, bsum, N);
    scan_top<<<1, 256, 0, stream>>>(bsum, boff, NB);
    scan_apply<<<NB, 256, 0, stream>>>(off, boff, cur, N, E);
    csr_fill<<<(E + 255) / 256, 256, 0, stream>>>(esrc, edst, ew, cur, srcs, ews, E);

    to_bf16_4<<<(N * F / 4 + 255) / 256, 256, 0, stream>>>(x, xh, N * F / 4);
    wtrans<<<H, F, 0, stream>>>(W1, Wt1, F, H);
    wtrans<<<H, H, 0, stream>>>(W2, Wt2, H, H);

    // ---- layer 1: S1 = A@x ; h1 = relu(S1@W1 + b1) ----
    spmm128<<<(N + 3) / 4, 256, 0, stream>>>(xh, off, srcs, ews, S1, N);
    gemm_mfma<128, true><<<(N / 16 + 3) / 4, 256, 0, stream>>>(S1, Wt1, b1, h1, N);

    // ---- layer 2: S2 = A@h1 ; h2 = relu(S2@W2 + b2) ----
    spmm256<<<(N + 3) / 4, 256, 0, stream>>>(h1, off, srcs, ews, S2, N);
    gemm_mfma<256, false><<<(N / 16 + 3) / 4, 256, 0, stream>>>(S2, Wt2, b2, h2, N);

    // ---- pool + head ----
    hipMemsetAsync(g, 0, (size_t)G * H * sizeof(float), stream);
    pool_seg<<<(N + 127) / 128, 256, 0, stream>>>(h2, seg, g, N);
    head_dense<<<G, 256, 0, stream>>>(g, Wd, bd, g2);
    head_out<<<G, 256, 0, stream>>>(g2, Wo, bo, out);
}

// Round 4
// 420.886 us; speedup vs baseline: 13.3639x; 1.1350x over previous
//
#include <hip/hip_runtime.h>
#include <hip/hip_bf16.h>

// ---------------------------------------------------------------------------
// TwoLayerGCN. Round 4: replace latency-bound per-wave GEMM (MfmaUtil 2.7%,
// 88.8us @ K=256 - B-frags re-read from global per wave) with 128x128
// LDS-tiled MFMA GEMM: 4 waves 2x2, BK=32, reg->LDS staging with next-tile
// global prefetch, 16 MFMA/wave/step, bias+relu fused. S1/S2 padded to
// 50048 rows so staging needs no predication; stores masked to row<M.
// ---------------------------------------------------------------------------

typedef short v8s __attribute__((ext_vector_type(8)));
typedef float v4f __attribute__((ext_vector_type(4)));

__device__ inline unsigned bf16u(float f) {           // fp32 -> bf16 bits (RNE)
    unsigned u = __builtin_bit_cast(unsigned, f);
    return (u + 0x7fffu + ((u >> 16) & 1u)) >> 16;
}
__device__ inline float bflo(unsigned v) { return __builtin_bit_cast(float, v << 16); }
__device__ inline float bfhi(unsigned v) { return __builtin_bit_cast(float, v & 0xffff0000u); }

// ----------------------------- conversions ---------------------------------

__global__ __launch_bounds__(256) void to_bf16_4(
    const float* __restrict__ in, ushort* __restrict__ out, int n4)
{
    int i = blockIdx.x * 256 + threadIdx.x;
    if (i >= n4) return;
    float4 v = ((const float4*)in)[i];
    unsigned lo = (bf16u(v.y) << 16) | bf16u(v.x);
    unsigned hi = (bf16u(v.w) << 16) | bf16u(v.z);
    ((uint2*)out)[i] = make_uint2(lo, hi);
}

// Wt[n*K+k] = bf16(W[k*N+n]); grid = N blocks, block = K threads
__global__ void wtrans(const float* __restrict__ W, ushort* __restrict__ Wt,
                       int K, int N)
{
    int n = blockIdx.x, k = threadIdx.x;
    Wt[n * K + k] = (ushort)bf16u(W[k * N + n]);
}

// ---------------- CSR-by-destination build (once per launch) ----------------

__global__ __launch_bounds__(256) void csr_hist(
    const int* __restrict__ dst, int* __restrict__ deg, int E)
{
    int e = blockIdx.x * 256 + threadIdx.x;
    if (e < E) atomicAdd(&deg[dst[e]], 1);
}

__global__ __launch_bounds__(256) void scan_block(
    const int* __restrict__ deg, int* __restrict__ off,
    int* __restrict__ blocksums, int n)
{
    __shared__ int s[256];
    int tid = threadIdx.x;
    int gid = blockIdx.x * 256 + tid;
    int v = (gid < n) ? deg[gid] : 0;
    s[tid] = v;
    __syncthreads();
    for (int o = 1; o < 256; o <<= 1) {
        int t = (tid >= o) ? s[tid - o] : 0;
        __syncthreads();
        s[tid] += t;
        __syncthreads();
    }
    if (gid < n) off[gid] = s[tid] - v;
    if (tid == 255) blocksums[blockIdx.x] = s[255];
}

__global__ __launch_bounds__(256) void scan_top(
    const int* __restrict__ blocksums, int* __restrict__ blockoffs, int nb)
{
    __shared__ int s[256];
    int tid = threadIdx.x;
    int v = (tid < nb) ? blocksums[tid] : 0;
    s[tid] = v;
    __syncthreads();
    for (int o = 1; o < 256; o <<= 1) {
        int t = (tid >= o) ? s[tid - o] : 0;
        __syncthreads();
        s[tid] += t;
        __syncthreads();
    }
    if (tid < nb) blockoffs[tid] = s[tid] - v;
}

__global__ __launch_bounds__(256) void scan_apply(
    int* __restrict__ off, const int* __restrict__ blockoffs,
    int* __restrict__ cursor, int n, int E)
{
    int gid = blockIdx.x * 256 + threadIdx.x;
    if (gid < n) {
        int v = off[gid] + blockoffs[gid >> 8];
        off[gid] = v;
        cursor[gid] = v;
    }
    if (gid == 0) off[n] = E;
}

__global__ __launch_bounds__(256) void csr_fill(
    const int* __restrict__ src, const int* __restrict__ dst,
    const float* __restrict__ w, int* __restrict__ cursor,
    int* __restrict__ srcs_s, float* __restrict__ ws_s, int E)
{
    int e = blockIdx.x * 256 + threadIdx.x;
    if (e >= E) return;
    int d = dst[e];
    int p = atomicAdd(&cursor[d], 1);
    srcs_s[p] = src[e];
    ws_s[p] = w[e];
}

// ----------------------- gather SpMM (bf16 in/out) --------------------------
// 128 feats: lane owns feats {2l, 2l+1} (one uint = 2 bf16), fp32 accum.
__global__ __launch_bounds__(256) void spmm128(
    const ushort* __restrict__ xh, const int* __restrict__ off,
    const int* __restrict__ srcs, const float* __restrict__ ew,
    ushort* __restrict__ S, int n)
{
    int node = blockIdx.x * 4 + (threadIdx.x >> 6);
    if (node >= n) return;
    int lane = threadIdx.x & 63;
    const unsigned* base = (const unsigned*)xh;   // row stride 64 uints
    int e0 = off[node], e1 = off[node + 1];
    float a0 = 0.f, a1 = 0.f;
    int e = e0;
    for (; e + 2 <= e1; e += 2) {
        int s0 = srcs[e], s1 = srcs[e + 1];
        float w0 = ew[e], w1 = ew[e + 1];
        unsigned v0 = base[(size_t)s0 * 64 + lane];
        unsigned v1 = base[(size_t)s1 * 64 + lane];
        a0 += bflo(v0) * w0 + bflo(v1) * w1;
        a1 += bfhi(v0) * w0 + bfhi(v1) * w1;
    }
    if (e < e1) {
        int s0 = srcs[e];
        float w0 = ew[e];
        unsigned v0 = base[(size_t)s0 * 64 + lane];
        a0 += bflo(v0) * w0;
        a1 += bfhi(v0) * w0;
    }
    ((unsigned*)S)[(size_t)node * 64 + lane] = (bf16u(a1) << 16) | bf16u(a0);
}

// 256 feats: lane owns feats {4l..4l+3} (uint2 = 4 bf16), fp32 accum.
__global__ __launch_bounds__(256) void spmm256(
    const ushort* __restrict__ hh, const int* __restrict__ off,
    const int* __restrict__ srcs, const float* __restrict__ ew,
    ushort* __restrict__ S, int n)
{
    int node = blockIdx.x * 4 + (threadIdx.x >> 6);
    if (node >= n) return;
    int lane = threadIdx.x & 63;
    const uint2* base = (const uint2*)hh;          // row stride 64 uint2
    int e0 = off[node], e1 = off[node + 1];
    float a0 = 0.f, a1 = 0.f, a2 = 0.f, a3 = 0.f;
    int e = e0;
    for (; e + 2 <= e1; e += 2) {
        int s0 = srcs[e], s1 = srcs[e + 1];
        float w0 = ew[e], w1 = ew[e + 1];
        uint2 v0 = base[(size_t)s0 * 64 + lane];
        uint2 v1 = base[(size_t)s1 * 64 + lane];
        a0 += bflo(v0.x) * w0 + bflo(v1.x) * w1;
        a1 += bfhi(v0.x) * w0 + bfhi(v1.x) * w1;
        a2 += bflo(v0.y) * w0 + bflo(v1.y) * w1;
        a3 += bfhi(v0.y) * w0 + bfhi(v1.y) * w1;
    }
    if (e < e1) {
        int s0 = srcs[e];
        float w0 = ew[e];
        uint2 v0 = base[(size_t)s0 * 64 + lane];
        a0 += bflo(v0.x) * w0;
        a1 += bfhi(v0.x) * w0;
        a2 += bflo(v0.y) * w0;
        a3 += bfhi(v0.y) * w0;
    }
    uint2 o;
    o.x = (bf16u(a1) << 16) | bf16u(a0);
    o.y = (bf16u(a3) << 16) | bf16u(a2);
    ((uint2*)S)[(size_t)node * 64 + lane] = o;
}

// ----------------------- LDS-tiled MFMA bf16 GEMM ---------------------------
// C[M,256] = relu(A[M,K] @ W + bias), A bf16 [Mpad,K] row-major,
// Wt bf16 [256,K] row-major (= W transposed). 128x128 tile per block,
// 4 waves 2x2, each wave 64x64 via 4x4 frags of 16x16x32. BK=32.
// Staging: thread t copies 2x16B of A-tile and B-tile (reg->ds_write_b128),
// prefetching the next K-step's 16B chunks before the compute barrier.
// Frag mapping (validated R3): lane(r=l&15,q=l>>4); A-frag=A[rowtile+r][q*8+j];
// B-frag=Wt[coltile+r][q*8+j]; D[row=q*4+i][col=r].
template <int K, bool BF16OUT>
__global__ __launch_bounds__(256) void gemm_tile(
    const ushort* __restrict__ A, const ushort* __restrict__ Wt,
    const float* __restrict__ bias, void* __restrict__ out, int M)
{
    __shared__ __align__(16) ushort As[128 * 32];
    __shared__ __align__(16) ushort Bs[128 * 32];

    const int tid = threadIdx.x;
    const int bm = blockIdx.x * 128;
    const int bn = blockIdx.y * 128;
    const int wave = tid >> 6, lane = tid & 63;
    const int wm = wave >> 1, wn = wave & 1;
    const int r = lane & 15, q = lane >> 4;

    // staging: byte offset o0 in the 8KB tile; row = o0>>6, 64B k-window
    const int o0 = tid * 16;
    const int row0 = o0 >> 6;          // 0..63  (chunk2: +64)
    const int kb0 = o0 & 63;           // byte offset within row's 64B window

    const char* Ab = (const char*)A;
    const char* Bb = (const char*)Wt;

    uint4 ra0, ra1, rb0, rb1;
    ra0 = *(const uint4*)(Ab + ((size_t)(bm + row0)      * K) * 2 + kb0);
    ra1 = *(const uint4*)(Ab + ((size_t)(bm + row0 + 64) * K) * 2 + kb0);
    rb0 = *(const uint4*)(Bb + ((size_t)(bn + row0)      * K) * 2 + kb0);
    rb1 = *(const uint4*)(Bb + ((size_t)(bn + row0 + 64) * K) * 2 + kb0);

    v4f acc[4][4];
    #pragma unroll
    for (int i = 0; i < 4; i++)
        #pragma unroll
        for (int j = 0; j < 4; j++) acc[i][j] = (v4f){0.f, 0.f, 0.f, 0.f};

    const int NK = K / 32;
    for (int ks = 0; ks < NK; ks++) {
        __syncthreads();               // previous compute done; LDS writable
        *(uint4*)((char*)As + o0)        = ra0;
        *(uint4*)((char*)As + o0 + 4096) = ra1;
        *(uint4*)((char*)Bs + o0)        = rb0;
        *(uint4*)((char*)Bs + o0 + 4096) = rb1;
        if (ks + 1 < NK) {             // prefetch next K-step
            const int kof = (ks + 1) * 64;   // bytes
            ra0 = *(const uint4*)(Ab + ((size_t)(bm + row0)      * K) * 2 + kof + kb0);
            ra1 = *(const uint4*)(Ab + ((size_t)(bm + row0 + 64) * K) * 2 + kof + kb0);
            rb0 = *(const uint4*)(Bb + ((size_t)(bn + row0)      * K) * 2 + kof + kb0);
            rb1 = *(const uint4*)(Bb + ((size_t)(bn + row0 + 64) * K) * 2 + kof + kb0);
        }
        __syncthreads();               // LDS tiles ready

        v8s af[4], bf[4];
        #pragma unroll
        for (int i = 0; i < 4; i++)
            af[i] = *(const v8s*)(As + (wm * 64 + i * 16 + r) * 32 + q * 8);
        #pragma unroll
        for (int j = 0; j < 4; j++)
            bf[j] = *(const v8s*)(Bs + (wn * 64 + j * 16 + r) * 32 + q * 8);
        #pragma unroll
        for (int i = 0; i < 4; i++)
            #pragma unroll
            for (int j = 0; j < 4; j++)
                acc[i][j] = __builtin_amdgcn_mfma_f32_16x16x32_bf16(
                    af[i], bf[j], acc[i][j], 0, 0, 0);
    }

    // epilogue: bias + relu, masked store
    #pragma unroll
    for (int j = 0; j < 4; j++) {
        int col = bn + wn * 64 + j * 16 + r;
        float b = bias[col];
        #pragma unroll
        for (int i = 0; i < 4; i++) {
            #pragma unroll
            for (int ii = 0; ii < 4; ii++) {
                int row = bm + wm * 64 + i * 16 + q * 4 + ii;
                if (row < M) {
                    float v = fmaxf(acc[i][j][ii] + b, 0.f);
                    if constexpr (BF16OUT)
                        ((ushort*)out)[(size_t)row * 256 + col] = (ushort)bf16u(v);
                    else
                        ((float*)out)[(size_t)row * 256 + col] = v;
                }
            }
        }
    }
}

// ------------------------------- pool + head --------------------------------

__global__ __launch_bounds__(256) void pool_seg(
    const float* __restrict__ h, const int* __restrict__ seg,
    float* __restrict__ g, int n_nodes)
{
    int f = threadIdx.x;
    int n0 = blockIdx.x * 128;
    int n1 = min(n0 + 128, n_nodes);
    float acc = 0.f;
    int cur = seg[n0];
    for (int n = n0; n < n1; n++) {
        int s = seg[n];
        if (s != cur) {
            atomicAdd(&g[(size_t)cur * 256 + f], acc);
            acc = 0.f;
            cur = s;
        }
        acc += h[(size_t)n * 256 + f];
    }
    atomicAdd(&g[(size_t)cur * 256 + f], acc);
}

__global__ __launch_bounds__(256) void head_dense(
    const float* __restrict__ g, const float* __restrict__ Wd,
    const float* __restrict__ bd, float* __restrict__ g2)
{
    __shared__ float gr[256];
    int j = threadIdx.x;
    int gi = blockIdx.x;
    gr[j] = g[(size_t)gi * 256 + j];
    __syncthreads();
    float acc = bd[j];
    for (int k = 0; k < 256; k++)
        acc += gr[k] * Wd[(size_t)k * 256 + j];
    g2[(size_t)gi * 256 + j] = fmaxf(acc, 0.f);
}

__global__ __launch_bounds__(256) void head_out(
    const float* __restrict__ g2, const float* __restrict__ Wo,
    const float* __restrict__ bo, float* __restrict__ out)
{
    int j = threadIdx.x;
    int gi = blockIdx.x;
    float v = g2[(size_t)gi * 256 + j] * Wo[j];
    #pragma unroll
    for (int off = 32; off > 0; off >>= 1)
        v += __shfl_down(v, off, 64);
    __shared__ float partial[4];
    if ((j & 63) == 0) partial[j >> 6] = v;
    __syncthreads();
    if (j == 0)
        out[gi] = partial[0] + partial[1] + partial[2] + partial[3] + bo[0];
}

extern "C" void kernel_launch(void* const* d_in, const int* in_sizes, int n_in,
                              void* d_out, int out_size, void* d_ws, size_t ws_size,
                              hipStream_t stream) {
    const float* x   = (const float*)d_in[0];
    const int*   esrc= (const int*)  d_in[1];
    const int*   edst= (const int*)  d_in[2];
    const float* ew  = (const float*)d_in[3];
    const int*   seg = (const int*)  d_in[4];
    const float* W1  = (const float*)d_in[5];
    const float* b1  = (const float*)d_in[6];
    const float* W2  = (const float*)d_in[7];
    const float* b2  = (const float*)d_in[8];
    const float* Wd  = (const float*)d_in[9];
    const float* bd  = (const float*)d_in[10];
    const float* Wo  = (const float*)d_in[11];
    const float* bo  = (const float*)d_in[12];
    float* out = (float*)d_out;

    const int N = 50000, E = 800000, G = 128, H = 256, F = 128;
    const int NPAD = 50048;            // 391 * 128
    const int NB = (N + 255) / 256;

    // workspace; region0 reused: {xh, S1} early, h2 (fp32) late
    char* p = (char*)d_ws;
    char* region0 = p;                  p += (size_t)N * H * sizeof(float);    // 51.2 MB
    ushort* xh = (ushort*)region0;                                             // [N,128] bf16
    ushort* S1 = (ushort*)(region0 + (size_t)N * F * sizeof(ushort));          // [NPAD,128] bf16
    float*  h2 = (float*)region0;                                              // [N,256] f32
    ushort* h1 = (ushort*)p;            p += (size_t)N * H * sizeof(ushort);   // [N,256] bf16
    ushort* S2 = (ushort*)p;            p += (size_t)NPAD * H * sizeof(ushort);// [NPAD,256] bf16
    float* g   = (float*)p;             p += (size_t)G * H * sizeof(float);
    float* g2  = (float*)p;             p += (size_t)G * H * sizeof(float);
    int*   deg = (int*)p;               p += (size_t)N * sizeof(int);
    int*   off = (int*)p;               p += (size_t)(N + 1) * sizeof(int) + 12;
    int*   cur = (int*)p;               p += (size_t)N * sizeof(int);
    int*   bsum= (int*)p;               p += 256 * sizeof(int);
    int*   boff= (int*)p;               p += 256 * sizeof(int);
    int*   srcs= (int*)p;               p += (size_t)E * sizeof(int);
    float* ews = (float*)p;             p += (size_t)E * sizeof(float);
    ushort* Wt1= (ushort*)p;            p += (size_t)H * F * sizeof(ushort);   // [256,128]
    ushort* Wt2= (ushort*)p;            p += (size_t)H * H * sizeof(ushort);   // [256,256]

    // ---- CSR build + weight/feature conversion ----
    hipMemsetAsync(deg, 0, (size_t)N * sizeof(int), stream);
    csr_hist<<<(E + 255) / 256, 256, 0, stream>>>(edst, deg, E);
    scan_block<<<NB, 256, 0, stream>>>(deg, off, bsum, N);
    scan_top<<<1, 256, 0, stream>>>(bsum, boff, NB);
    scan_apply<<<NB, 256, 0, stream>>>(off, boff, cur, N, E);
    csr_fill<<<(E + 255) / 256, 256, 0, stream>>>(esrc, edst, ew, cur, srcs, ews, E);

    to_bf16_4<<<(N * F / 4 + 255) / 256, 256, 0, stream>>>(x, xh, N * F / 4);
    wtrans<<<H, F, 0, stream>>>(W1, Wt1, F, H);
    wtrans<<<H, H, 0, stream>>>(W2, Wt2, H, H);

    // ---- layer 1: S1 = A@x ; h1 = relu(S1@W1 + b1) ----
    spmm128<<<(N + 3) / 4, 256, 0, stream>>>(xh, off, srcs, ews, S1, N);
    gemm_tile<128, true><<<dim3(NPAD / 128, 2), 256, 0, stream>>>(S1, Wt1, b1, h1, N);

    // ---- layer 2: S2 = A@h1 ; h2 = relu(S2@W2 + b2) ----
    spmm256<<<(N + 3) / 4, 256, 0, stream>>>(h1, off, srcs, ews, S2, N);
    gemm_tile<256, false><<<dim3(NPAD / 128, 2), 256, 0, stream>>>(S2, Wt2, b2, h2, N);

    // ---- pool + head ----
    hipMemsetAsync(g, 0, (size_t)G * H * sizeof(float), stream);
    pool_seg<<<(N + 127) / 128, 256, 0, stream>>>(h2, seg, g, N);
    head_dense<<<G, 256, 0, stream>>>(g, Wd, bd, g2);
    head_out<<<G, 256, 0, stream>>>(g2, Wo, bo, out);
}

// Round 5
// 395.423 us; speedup vs baseline: 14.2245x; 1.0644x over previous
//
#include <hip/hip_runtime.h>
#include <hip/hip_bf16.h>

// ---------------------------------------------------------------------------
// TwoLayerGCN. Round 5: spmm gather kernels unrolled x4 (batched index +
// row loads -> 4 independent 512B/256B loads in flight per wave).
// R4 counters: spmm256 64.9us, 40% HBM peak, latency-bound (2 loads in
// flight; R2 fp32 with 2x bytes/load hit 48% - bytes-in-flight scaling).
// ---------------------------------------------------------------------------

typedef short v8s __attribute__((ext_vector_type(8)));
typedef float v4f __attribute__((ext_vector_type(4)));

__device__ inline unsigned bf16u(float f) {           // fp32 -> bf16 bits (RNE)
    unsigned u = __builtin_bit_cast(unsigned, f);
    return (u + 0x7fffu + ((u >> 16) & 1u)) >> 16;
}
__device__ inline float bflo(unsigned v) { return __builtin_bit_cast(float, v << 16); }
__device__ inline float bfhi(unsigned v) { return __builtin_bit_cast(float, v & 0xffff0000u); }

// ----------------------------- conversions ---------------------------------

__global__ __launch_bounds__(256) void to_bf16_4(
    const float* __restrict__ in, ushort* __restrict__ out, int n4)
{
    int i = blockIdx.x * 256 + threadIdx.x;
    if (i >= n4) return;
    float4 v = ((const float4*)in)[i];
    unsigned lo = (bf16u(v.y) << 16) | bf16u(v.x);
    unsigned hi = (bf16u(v.w) << 16) | bf16u(v.z);
    ((uint2*)out)[i] = make_uint2(lo, hi);
}

// Wt[n*K+k] = bf16(W[k*N+n]); grid = N blocks, block = K threads
__global__ void wtrans(const float* __restrict__ W, ushort* __restrict__ Wt,
                       int K, int N)
{
    int n = blockIdx.x, k = threadIdx.x;
    Wt[n * K + k] = (ushort)bf16u(W[k * N + n]);
}

// ---------------- CSR-by-destination build (once per launch) ----------------

__global__ __launch_bounds__(256) void csr_hist(
    const int* __restrict__ dst, int* __restrict__ deg, int E)
{
    int e = blockIdx.x * 256 + threadIdx.x;
    if (e < E) atomicAdd(&deg[dst[e]], 1);
}

__global__ __launch_bounds__(256) void scan_block(
    const int* __restrict__ deg, int* __restrict__ off,
    int* __restrict__ blocksums, int n)
{
    __shared__ int s[256];
    int tid = threadIdx.x;
    int gid = blockIdx.x * 256 + tid;
    int v = (gid < n) ? deg[gid] : 0;
    s[tid] = v;
    __syncthreads();
    for (int o = 1; o < 256; o <<= 1) {
        int t = (tid >= o) ? s[tid - o] : 0;
        __syncthreads();
        s[tid] += t;
        __syncthreads();
    }
    if (gid < n) off[gid] = s[tid] - v;
    if (tid == 255) blocksums[blockIdx.x] = s[255];
}

__global__ __launch_bounds__(256) void scan_top(
    const int* __restrict__ blocksums, int* __restrict__ blockoffs, int nb)
{
    __shared__ int s[256];
    int tid = threadIdx.x;
    int v = (tid < nb) ? blocksums[tid] : 0;
    s[tid] = v;
    __syncthreads();
    for (int o = 1; o < 256; o <<= 1) {
        int t = (tid >= o) ? s[tid - o] : 0;
        __syncthreads();
        s[tid] += t;
        __syncthreads();
    }
    if (tid < nb) blockoffs[tid] = s[tid] - v;
}

__global__ __launch_bounds__(256) void scan_apply(
    int* __restrict__ off, const int* __restrict__ blockoffs,
    int* __restrict__ cursor, int n, int E)
{
    int gid = blockIdx.x * 256 + threadIdx.x;
    if (gid < n) {
        int v = off[gid] + blockoffs[gid >> 8];
        off[gid] = v;
        cursor[gid] = v;
    }
    if (gid == 0) off[n] = E;
}

__global__ __launch_bounds__(256) void csr_fill(
    const int* __restrict__ src, const int* __restrict__ dst,
    const float* __restrict__ w, int* __restrict__ cursor,
    int* __restrict__ srcs_s, float* __restrict__ ws_s, int E)
{
    int e = blockIdx.x * 256 + threadIdx.x;
    if (e >= E) return;
    int d = dst[e];
    int p = atomicAdd(&cursor[d], 1);
    srcs_s[p] = src[e];
    ws_s[p] = w[e];
}

// ----------------------- gather SpMM (bf16 in/out) --------------------------
// 128 feats: lane owns feats {2l, 2l+1} (one uint = 2 bf16), fp32 accum.
// Unroll x4: 4 independent row loads in flight before any FMA.
__global__ __launch_bounds__(256) void spmm128(
    const ushort* __restrict__ xh, const int* __restrict__ off,
    const int* __restrict__ srcs, const float* __restrict__ ew,
    ushort* __restrict__ S, int n)
{
    int node = blockIdx.x * 4 + (threadIdx.x >> 6);
    if (node >= n) return;
    int lane = threadIdx.x & 63;
    const unsigned* base = (const unsigned*)xh;   // row stride 64 uints
    int e0 = off[node], e1 = off[node + 1];
    float a0 = 0.f, a1 = 0.f;
    int e = e0;
    for (; e + 4 <= e1; e += 4) {
        int s0 = srcs[e], s1 = srcs[e + 1], s2 = srcs[e + 2], s3 = srcs[e + 3];
        float w0 = ew[e], w1 = ew[e + 1], w2 = ew[e + 2], w3 = ew[e + 3];
        unsigned v0 = base[(size_t)s0 * 64 + lane];
        unsigned v1 = base[(size_t)s1 * 64 + lane];
        unsigned v2 = base[(size_t)s2 * 64 + lane];
        unsigned v3 = base[(size_t)s3 * 64 + lane];
        a0 += bflo(v0) * w0 + bflo(v1) * w1 + bflo(v2) * w2 + bflo(v3) * w3;
        a1 += bfhi(v0) * w0 + bfhi(v1) * w1 + bfhi(v2) * w2 + bfhi(v3) * w3;
    }
    for (; e < e1; e++) {
        int s0 = srcs[e];
        float w0 = ew[e];
        unsigned v0 = base[(size_t)s0 * 64 + lane];
        a0 += bflo(v0) * w0;
        a1 += bfhi(v0) * w0;
    }
    ((unsigned*)S)[(size_t)node * 64 + lane] = (bf16u(a1) << 16) | bf16u(a0);
}

// 256 feats: lane owns feats {4l..4l+3} (uint2 = 4 bf16), fp32 accum.
// Unroll x4.
__global__ __launch_bounds__(256) void spmm256(
    const ushort* __restrict__ hh, const int* __restrict__ off,
    const int* __restrict__ srcs, const float* __restrict__ ew,
    ushort* __restrict__ S, int n)
{
    int node = blockIdx.x * 4 + (threadIdx.x >> 6);
    if (node >= n) return;
    int lane = threadIdx.x & 63;
    const uint2* base = (const uint2*)hh;          // row stride 64 uint2
    int e0 = off[node], e1 = off[node + 1];
    float a0 = 0.f, a1 = 0.f, a2 = 0.f, a3 = 0.f;
    int e = e0;
    for (; e + 4 <= e1; e += 4) {
        int s0 = srcs[e], s1 = srcs[e + 1], s2 = srcs[e + 2], s3 = srcs[e + 3];
        float w0 = ew[e], w1 = ew[e + 1], w2 = ew[e + 2], w3 = ew[e + 3];
        uint2 v0 = base[(size_t)s0 * 64 + lane];
        uint2 v1 = base[(size_t)s1 * 64 + lane];
        uint2 v2 = base[(size_t)s2 * 64 + lane];
        uint2 v3 = base[(size_t)s3 * 64 + lane];
        a0 += bflo(v0.x) * w0 + bflo(v1.x) * w1 + bflo(v2.x) * w2 + bflo(v3.x) * w3;
        a1 += bfhi(v0.x) * w0 + bfhi(v1.x) * w1 + bfhi(v2.x) * w2 + bfhi(v3.x) * w3;
        a2 += bflo(v0.y) * w0 + bflo(v1.y) * w1 + bflo(v2.y) * w2 + bflo(v3.y) * w3;
        a3 += bfhi(v0.y) * w0 + bfhi(v1.y) * w1 + bfhi(v2.y) * w2 + bfhi(v3.y) * w3;
    }
    for (; e < e1; e++) {
        int s0 = srcs[e];
        float w0 = ew[e];
        uint2 v0 = base[(size_t)s0 * 64 + lane];
        a0 += bflo(v0.x) * w0;
        a1 += bfhi(v0.x) * w0;
        a2 += bflo(v0.y) * w0;
        a3 += bfhi(v0.y) * w0;
    }
    uint2 o;
    o.x = (bf16u(a1) << 16) | bf16u(a0);
    o.y = (bf16u(a3) << 16) | bf16u(a2);
    ((uint2*)S)[(size_t)node * 64 + lane] = o;
}

// ----------------------- LDS-tiled MFMA bf16 GEMM ---------------------------
// C[M,256] = relu(A[M,K] @ W + bias), A bf16 [Mpad,K] row-major,
// Wt bf16 [256,K] row-major (= W transposed). 128x128 tile per block,
// 4 waves 2x2, each wave 64x64 via 4x4 frags of 16x16x32. BK=32.
template <int K, bool BF16OUT>
__global__ __launch_bounds__(256) void gemm_tile(
    const ushort* __restrict__ A, const ushort* __restrict__ Wt,
    const float* __restrict__ bias, void* __restrict__ out, int M)
{
    __shared__ __align__(16) ushort As[128 * 32];
    __shared__ __align__(16) ushort Bs[128 * 32];

    const int tid = threadIdx.x;
    const int bm = blockIdx.x * 128;
    const int bn = blockIdx.y * 128;
    const int wave = tid >> 6, lane = tid & 63;
    const int wm = wave >> 1, wn = wave & 1;
    const int r = lane & 15, q = lane >> 4;

    const int o0 = tid * 16;
    const int row0 = o0 >> 6;
    const int kb0 = o0 & 63;

    const char* Ab = (const char*)A;
    const char* Bb = (const char*)Wt;

    uint4 ra0, ra1, rb0, rb1;
    ra0 = *(const uint4*)(Ab + ((size_t)(bm + row0)      * K) * 2 + kb0);
    ra1 = *(const uint4*)(Ab + ((size_t)(bm + row0 + 64) * K) * 2 + kb0);
    rb0 = *(const uint4*)(Bb + ((size_t)(bn + row0)      * K) * 2 + kb0);
    rb1 = *(const uint4*)(Bb + ((size_t)(bn + row0 + 64) * K) * 2 + kb0);

    v4f acc[4][4];
    #pragma unroll
    for (int i = 0; i < 4; i++)
        #pragma unroll
        for (int j = 0; j < 4; j++) acc[i][j] = (v4f){0.f, 0.f, 0.f, 0.f};

    const int NK = K / 32;
    for (int ks = 0; ks < NK; ks++) {
        __syncthreads();
        *(uint4*)((char*)As + o0)        = ra0;
        *(uint4*)((char*)As + o0 + 4096) = ra1;
        *(uint4*)((char*)Bs + o0)        = rb0;
        *(uint4*)((char*)Bs + o0 + 4096) = rb1;
        if (ks + 1 < NK) {
            const int kof = (ks + 1) * 64;
            ra0 = *(const uint4*)(Ab + ((size_t)(bm + row0)      * K) * 2 + kof + kb0);
            ra1 = *(const uint4*)(Ab + ((size_t)(bm + row0 + 64) * K) * 2 + kof + kb0);
            rb0 = *(const uint4*)(Bb + ((size_t)(bn + row0)      * K) * 2 + kof + kb0);
            rb1 = *(const uint4*)(Bb + ((size_t)(bn + row0 + 64) * K) * 2 + kof + kb0);
        }
        __syncthreads();

        v8s af[4], bf[4];
        #pragma unroll
        for (int i = 0; i < 4; i++)
            af[i] = *(const v8s*)(As + (wm * 64 + i * 16 + r) * 32 + q * 8);
        #pragma unroll
        for (int j = 0; j < 4; j++)
            bf[j] = *(const v8s*)(Bs + (wn * 64 + j * 16 + r) * 32 + q * 8);
        #pragma unroll
        for (int i = 0; i < 4; i++)
            #pragma unroll
            for (int j = 0; j < 4; j++)
                acc[i][j] = __builtin_amdgcn_mfma_f32_16x16x32_bf16(
                    af[i], bf[j], acc[i][j], 0, 0, 0);
    }

    #pragma unroll
    for (int j = 0; j < 4; j++) {
        int col = bn + wn * 64 + j * 16 + r;
        float b = bias[col];
        #pragma unroll
        for (int i = 0; i < 4; i++) {
            #pragma unroll
            for (int ii = 0; ii < 4; ii++) {
                int row = bm + wm * 64 + i * 16 + q * 4 + ii;
                if (row < M) {
                    float v = fmaxf(acc[i][j][ii] + b, 0.f);
                    if constexpr (BF16OUT)
                        ((ushort*)out)[(size_t)row * 256 + col] = (ushort)bf16u(v);
                    else
                        ((float*)out)[(size_t)row * 256 + col] = v;
                }
            }
        }
    }
}

// ------------------------------- pool + head --------------------------------

__global__ __launch_bounds__(256) void pool_seg(
    const float* __restrict__ h, const int* __restrict__ seg,
    float* __restrict__ g, int n_nodes)
{
    int f = threadIdx.x;
    int n0 = blockIdx.x * 128;
    int n1 = min(n0 + 128, n_nodes);
    float acc = 0.f;
    int cur = seg[n0];
    for (int n = n0; n < n1; n++) {
        int s = seg[n];
        if (s != cur) {
            atomicAdd(&g[(size_t)cur * 256 + f], acc);
            acc = 0.f;
            cur = s;
        }
        acc += h[(size_t)n * 256 + f];
    }
    atomicAdd(&g[(size_t)cur * 256 + f], acc);
}

__global__ __launch_bounds__(256) void head_dense(
    const float* __restrict__ g, const float* __restrict__ Wd,
    const float* __restrict__ bd, float* __restrict__ g2)
{
    __shared__ float gr[256];
    int j = threadIdx.x;
    int gi = blockIdx.x;
    gr[j] = g[(size_t)gi * 256 + j];
    __syncthreads();
    float acc = bd[j];
    for (int k = 0; k < 256; k++)
        acc += gr[k] * Wd[(size_t)k * 256 + j];
    g2[(size_t)gi * 256 + j] = fmaxf(acc, 0.f);
}

__global__ __launch_bounds__(256) void head_out(
    const float* __restrict__ g2, const float* __restrict__ Wo,
    const float* __restrict__ bo, float* __restrict__ out)
{
    int j = threadIdx.x;
    int gi = blockIdx.x;
    float v = g2[(size_t)gi * 256 + j] * Wo[j];
    #pragma unroll
    for (int off = 32; off > 0; off >>= 1)
        v += __shfl_down(v, off, 64);
    __shared__ float partial[4];
    if ((j & 63) == 0) partial[j >> 6] = v;
    __syncthreads();
    if (j == 0)
        out[gi] = partial[0] + partial[1] + partial[2] + partial[3] + bo[0];
}

extern "C" void kernel_launch(void* const* d_in, const int* in_sizes, int n_in,
                              void* d_out, int out_size, void* d_ws, size_t ws_size,
                              hipStream_t stream) {
    const float* x   = (const float*)d_in[0];
    const int*   esrc= (const int*)  d_in[1];
    const int*   edst= (const int*)  d_in[2];
    const float* ew  = (const float*)d_in[3];
    const int*   seg = (const int*)  d_in[4];
    const float* W1  = (const float*)d_in[5];
    const float* b1  = (const float*)d_in[6];
    const float* W2  = (const float*)d_in[7];
    const float* b2  = (const float*)d_in[8];
    const float* Wd  = (const float*)d_in[9];
    const float* bd  = (const float*)d_in[10];
    const float* Wo  = (const float*)d_in[11];
    const float* bo  = (const float*)d_in[12];
    float* out = (float*)d_out;

    const int N = 50000, E = 800000, G = 128, H = 256, F = 128;
    const int NPAD = 50048;            // 391 * 128
    const int NB = (N + 255) / 256;

    // workspace; region0 reused: {xh, S1} early, h2 (fp32) late
    char* p = (char*)d_ws;
    char* region0 = p;                  p += (size_t)N * H * sizeof(float);    // 51.2 MB
    ushort* xh = (ushort*)region0;                                             // [N,128] bf16
    ushort* S1 = (ushort*)(region0 + (size_t)N * F * sizeof(ushort));          // [NPAD,128] bf16
    float*  h2 = (float*)region0;                                              // [N,256] f32
    ushort* h1 = (ushort*)p;            p += (size_t)N * H * sizeof(ushort);   // [N,256] bf16
    ushort* S2 = (ushort*)p;            p += (size_t)NPAD * H * sizeof(ushort);// [NPAD,256] bf16
    float* g   = (float*)p;             p += (size_t)G * H * sizeof(float);
    float* g2  = (float*)p;             p += (size_t)G * H * sizeof(float);
    int*   deg = (int*)p;               p += (size_t)N * sizeof(int);
    int*   off = (int*)p;               p += (size_t)(N + 1) * sizeof(int) + 12;
    int*   cur = (int*)p;               p += (size_t)N * sizeof(int);
    int*   bsum= (int*)p;               p += 256 * sizeof(int);
    int*   boff= (int*)p;               p += 256 * sizeof(int);
    int*   srcs= (int*)p;               p += (size_t)E * sizeof(int);
    float* ews = (float*)p;             p += (size_t)E * sizeof(float);
    ushort* Wt1= (ushort*)p;            p += (size_t)H * F * sizeof(ushort);   // [256,128]
    ushort* Wt2= (ushort*)p;            p += (size_t)H * H * sizeof(ushort);   // [256,256]

    // ---- CSR build + weight/feature conversion ----
    hipMemsetAsync(deg, 0, (size_t)N * sizeof(int), stream);
    csr_hist<<<(E + 255) / 256, 256, 0, stream>>>(edst, deg, E);
    scan_block<<<NB, 256, 0, stream>>>(deg, off, bsum, N);
    scan_top<<<1, 256, 0, stream>>>(bsum, boff, NB);
    scan_apply<<<NB, 256, 0, stream>>>(off, boff, cur, N, E);
    csr_fill<<<(E + 255) / 256, 256, 0, stream>>>(esrc, edst, ew, cur, srcs, ews, E);

    to_bf16_4<<<(N * F / 4 + 255) / 256, 256, 0, stream>>>(x, xh, N * F / 4);
    wtrans<<<H, F, 0, stream>>>(W1, Wt1, F, H);
    wtrans<<<H, H, 0, stream>>>(W2, Wt2, H, H);

    // ---- layer 1: S1 = A@x ; h1 = relu(S1@W1 + b1) ----
    spmm128<<<(N + 3) / 4, 256, 0, stream>>>(xh, off, srcs, ews, S1, N);
    gemm_tile<128, true><<<dim3(NPAD / 128, 2), 256, 0, stream>>>(S1, Wt1, b1, h1, N);

    // ---- layer 2: S2 = A@h1 ; h2 = relu(S2@W2 + b2) ----
    spmm256<<<(N + 3) / 4, 256, 0, stream>>>(h1, off, srcs, ews, S2, N);
    gemm_tile<256, false><<<dim3(NPAD / 128, 2), 256, 0, stream>>>(S2, Wt2, b2, h2, N);

    // ---- pool + head ----
    hipMemsetAsync(g, 0, (size_t)G * H * sizeof(float), stream);
    pool_seg<<<(N + 127) / 128, 256, 0, stream>>>(h2, seg, g, N);
    head_dense<<<G, 256, 0, stream>>>(g, Wd, bd, g2);
    head_out<<<G, 256, 0, stream>>>(g2, Wo, bo, out);
}

// Round 6
// 380.140 us; speedup vs baseline: 14.7964x; 1.0402x over previous
//
#include <hip/hip_runtime.h>
#include <hip/hip_bf16.h>

// ---------------------------------------------------------------------------
// TwoLayerGCN. Round 6:
//  - csr_fill: pack (src,w) -> single uint2 scattered store (R5: 82 MB
//    WRITE_SIZE from 1.6M 4B stores @ 64B sectors; halves sector count)
//  - fuse scan_top into scan_apply; fuse 2x wtrans; fuse pool+head (seg_ids
//    sorted -> per-graph contiguous range via binary search, no atomics)
//  - dispatch count 17 -> 12
// ---------------------------------------------------------------------------

typedef short v8s __attribute__((ext_vector_type(8)));
typedef float v4f __attribute__((ext_vector_type(4)));

__device__ inline unsigned bf16u(float f) {           // fp32 -> bf16 bits (RNE)
    unsigned u = __builtin_bit_cast(unsigned, f);
    return (u + 0x7fffu + ((u >> 16) & 1u)) >> 16;
}
__device__ inline float bflo(unsigned v) { return __builtin_bit_cast(float, v << 16); }
__device__ inline float bfhi(unsigned v) { return __builtin_bit_cast(float, v & 0xffff0000u); }
__device__ inline float f32bits(unsigned v) { return __builtin_bit_cast(float, v); }

// ----------------------------- conversions ---------------------------------

__global__ __launch_bounds__(256) void to_bf16_4(
    const float* __restrict__ in, ushort* __restrict__ out, int n4)
{
    int i = blockIdx.x * 256 + threadIdx.x;
    if (i >= n4) return;
    float4 v = ((const float4*)in)[i];
    unsigned lo = (bf16u(v.y) << 16) | bf16u(v.x);
    unsigned hi = (bf16u(v.w) << 16) | bf16u(v.z);
    ((uint2*)out)[i] = make_uint2(lo, hi);
}

// blocks [0,256): Wt1[n*128+k] = bf16(W1[k*256+n]) (threads<128)
// blocks [256,512): Wt2[n*256+k] = bf16(W2[k*256+n])
__global__ __launch_bounds__(256) void wtrans2(
    const float* __restrict__ W1, ushort* __restrict__ Wt1,
    const float* __restrict__ W2, ushort* __restrict__ Wt2)
{
    int b = blockIdx.x, k = threadIdx.x;
    if (b < 256) {
        if (k < 128) Wt1[b * 128 + k] = (ushort)bf16u(W1[k * 256 + b]);
    } else {
        int n = b - 256;
        Wt2[n * 256 + k] = (ushort)bf16u(W2[k * 256 + n]);
    }
}

// ---------------- CSR-by-destination build (once per launch) ----------------

__global__ __launch_bounds__(256) void csr_hist(
    const int* __restrict__ dst, int* __restrict__ deg, int E)
{
    int e = blockIdx.x * 256 + threadIdx.x;
    if (e < E) atomicAdd(&deg[dst[e]], 1);
}

__global__ __launch_bounds__(256) void scan_block(
    const int* __restrict__ deg, int* __restrict__ off,
    int* __restrict__ blocksums, int n)
{
    __shared__ int s[256];
    int tid = threadIdx.x;
    int gid = blockIdx.x * 256 + tid;
    int v = (gid < n) ? deg[gid] : 0;
    s[tid] = v;
    __syncthreads();
    for (int o = 1; o < 256; o <<= 1) {
        int t = (tid >= o) ? s[tid - o] : 0;
        __syncthreads();
        s[tid] += t;
        __syncthreads();
    }
    if (gid < n) off[gid] = s[tid] - v;
    if (tid == 255) blocksums[blockIdx.x] = s[255];
}

// fused: every block redundantly scans the <=256 block sums in LDS, then
// applies its own exclusive block offset. (replaces scan_top + scan_apply)
__global__ __launch_bounds__(256) void scan_apply(
    int* __restrict__ off, const int* __restrict__ blocksums,
    int* __restrict__ cursor, int n, int E, int nb)
{
    __shared__ int s[256];
    int tid = threadIdx.x;
    int v = (tid < nb) ? blocksums[tid] : 0;
    s[tid] = v;
    __syncthreads();
    for (int o = 1; o < 256; o <<= 1) {
        int t = (tid >= o) ? s[tid - o] : 0;
        __syncthreads();
        s[tid] += t;
        __syncthreads();
    }
    int b = blockIdx.x;
    int boff = (b == 0) ? 0 : s[b - 1];
    int gid = b * 256 + tid;
    if (gid < n) {
        int w = off[gid] + boff;
        off[gid] = w;
        cursor[gid] = w;
    }
    if (gid == 0) off[n] = E;
}

__global__ __launch_bounds__(256) void csr_fill(
    const int* __restrict__ src, const int* __restrict__ dst,
    const float* __restrict__ w, int* __restrict__ cursor,
    uint2* __restrict__ edges, int E)
{
    int e = blockIdx.x * 256 + threadIdx.x;
    if (e >= E) return;
    int d = dst[e];
    int p = atomicAdd(&cursor[d], 1);
    edges[p] = make_uint2((unsigned)src[e],
                          __builtin_bit_cast(unsigned, w[e]));
}

// ----------------------- gather SpMM (bf16 in/out) --------------------------
// 128 feats: lane owns feats {2l, 2l+1}; unroll x4 (4 row loads in flight).
__global__ __launch_bounds__(256) void spmm128(
    const ushort* __restrict__ xh, const int* __restrict__ off,
    const uint2* __restrict__ edges, ushort* __restrict__ S, int n)
{
    int node = blockIdx.x * 4 + (threadIdx.x >> 6);
    if (node >= n) return;
    int lane = threadIdx.x & 63;
    const unsigned* base = (const unsigned*)xh;   // row stride 64 uints
    int e0 = off[node], e1 = off[node + 1];
    float a0 = 0.f, a1 = 0.f;
    int e = e0;
    for (; e + 4 <= e1; e += 4) {
        uint2 ed0 = edges[e],     ed1 = edges[e + 1];
        uint2 ed2 = edges[e + 2], ed3 = edges[e + 3];
        float w0 = f32bits(ed0.y), w1 = f32bits(ed1.y);
        float w2 = f32bits(ed2.y), w3 = f32bits(ed3.y);
        unsigned v0 = base[(size_t)ed0.x * 64 + lane];
        unsigned v1 = base[(size_t)ed1.x * 64 + lane];
        unsigned v2 = base[(size_t)ed2.x * 64 + lane];
        unsigned v3 = base[(size_t)ed3.x * 64 + lane];
        a0 += bflo(v0) * w0 + bflo(v1) * w1 + bflo(v2) * w2 + bflo(v3) * w3;
        a1 += bfhi(v0) * w0 + bfhi(v1) * w1 + bfhi(v2) * w2 + bfhi(v3) * w3;
    }
    for (; e < e1; e++) {
        uint2 ed = edges[e];
        float w0 = f32bits(ed.y);
        unsigned v0 = base[(size_t)ed.x * 64 + lane];
        a0 += bflo(v0) * w0;
        a1 += bfhi(v0) * w0;
    }
    ((unsigned*)S)[(size_t)node * 64 + lane] = (bf16u(a1) << 16) | bf16u(a0);
}

// 256 feats: lane owns feats {4l..4l+3}; unroll x4.
__global__ __launch_bounds__(256) void spmm256(
    const ushort* __restrict__ hh, const int* __restrict__ off,
    const uint2* __restrict__ edges, ushort* __restrict__ S, int n)
{
    int node = blockIdx.x * 4 + (threadIdx.x >> 6);
    if (node >= n) return;
    int lane = threadIdx.x & 63;
    const uint2* base = (const uint2*)hh;          // row stride 64 uint2
    int e0 = off[node], e1 = off[node + 1];
    float a0 = 0.f, a1 = 0.f, a2 = 0.f, a3 = 0.f;
    int e = e0;
    for (; e + 4 <= e1; e += 4) {
        uint2 ed0 = edges[e],     ed1 = edges[e + 1];
        uint2 ed2 = edges[e + 2], ed3 = edges[e + 3];
        float w0 = f32bits(ed0.y), w1 = f32bits(ed1.y);
        float w2 = f32bits(ed2.y), w3 = f32bits(ed3.y);
        uint2 v0 = base[(size_t)ed0.x * 64 + lane];
        uint2 v1 = base[(size_t)ed1.x * 64 + lane];
        uint2 v2 = base[(size_t)ed2.x * 64 + lane];
        uint2 v3 = base[(size_t)ed3.x * 64 + lane];
        a0 += bflo(v0.x) * w0 + bflo(v1.x) * w1 + bflo(v2.x) * w2 + bflo(v3.x) * w3;
        a1 += bfhi(v0.x) * w0 + bfhi(v1.x) * w1 + bfhi(v2.x) * w2 + bfhi(v3.x) * w3;
        a2 += bflo(v0.y) * w0 + bflo(v1.y) * w1 + bflo(v2.y) * w2 + bflo(v3.y) * w3;
        a3 += bfhi(v0.y) * w0 + bfhi(v1.y) * w1 + bfhi(v2.y) * w2 + bfhi(v3.y) * w3;
    }
    for (; e < e1; e++) {
        uint2 ed = edges[e];
        float w0 = f32bits(ed.y);
        uint2 v0 = base[(size_t)ed.x * 64 + lane];
        a0 += bflo(v0.x) * w0;
        a1 += bfhi(v0.x) * w0;
        a2 += bflo(v0.y) * w0;
        a3 += bfhi(v0.y) * w0;
    }
    uint2 o;
    o.x = (bf16u(a1) << 16) | bf16u(a0);
    o.y = (bf16u(a3) << 16) | bf16u(a2);
    ((uint2*)S)[(size_t)node * 64 + lane] = o;
}

// ----------------------- LDS-tiled MFMA bf16 GEMM ---------------------------
template <int K, bool BF16OUT>
__global__ __launch_bounds__(256) void gemm_tile(
    const ushort* __restrict__ A, const ushort* __restrict__ Wt,
    const float* __restrict__ bias, void* __restrict__ out, int M)
{
    __shared__ __align__(16) ushort As[128 * 32];
    __shared__ __align__(16) ushort Bs[128 * 32];

    const int tid = threadIdx.x;
    const int bm = blockIdx.x * 128;
    const int bn = blockIdx.y * 128;
    const int wave = tid >> 6, lane = tid & 63;
    const int wm = wave >> 1, wn = wave & 1;
    const int r = lane & 15, q = lane >> 4;

    const int o0 = tid * 16;
    const int row0 = o0 >> 6;
    const int kb0 = o0 & 63;

    const char* Ab = (const char*)A;
    const char* Bb = (const char*)Wt;

    uint4 ra0, ra1, rb0, rb1;
    ra0 = *(const uint4*)(Ab + ((size_t)(bm + row0)      * K) * 2 + kb0);
    ra1 = *(const uint4*)(Ab + ((size_t)(bm + row0 + 64) * K) * 2 + kb0);
    rb0 = *(const uint4*)(Bb + ((size_t)(bn + row0)      * K) * 2 + kb0);
    rb1 = *(const uint4*)(Bb + ((size_t)(bn + row0 + 64) * K) * 2 + kb0);

    v4f acc[4][4];
    #pragma unroll
    for (int i = 0; i < 4; i++)
        #pragma unroll
        for (int j = 0; j < 4; j++) acc[i][j] = (v4f){0.f, 0.f, 0.f, 0.f};

    const int NK = K / 32;
    for (int ks = 0; ks < NK; ks++) {
        __syncthreads();
        *(uint4*)((char*)As + o0)        = ra0;
        *(uint4*)((char*)As + o0 + 4096) = ra1;
        *(uint4*)((char*)Bs + o0)        = rb0;
        *(uint4*)((char*)Bs + o0 + 4096) = rb1;
        if (ks + 1 < NK) {
            const int kof = (ks + 1) * 64;
            ra0 = *(const uint4*)(Ab + ((size_t)(bm + row0)      * K) * 2 + kof + kb0);
            ra1 = *(const uint4*)(Ab + ((size_t)(bm + row0 + 64) * K) * 2 + kof + kb0);
            rb0 = *(const uint4*)(Bb + ((size_t)(bn + row0)      * K) * 2 + kof + kb0);
            rb1 = *(const uint4*)(Bb + ((size_t)(bn + row0 + 64) * K) * 2 + kof + kb0);
        }
        __syncthreads();

        v8s af[4], bf[4];
        #pragma unroll
        for (int i = 0; i < 4; i++)
            af[i] = *(const v8s*)(As + (wm * 64 + i * 16 + r) * 32 + q * 8);
        #pragma unroll
        for (int j = 0; j < 4; j++)
            bf[j] = *(const v8s*)(Bs + (wn * 64 + j * 16 + r) * 32 + q * 8);
        #pragma unroll
        for (int i = 0; i < 4; i++)
            #pragma unroll
            for (int j = 0; j < 4; j++)
                acc[i][j] = __builtin_amdgcn_mfma_f32_16x16x32_bf16(
                    af[i], bf[j], acc[i][j], 0, 0, 0);
    }

    #pragma unroll
    for (int j = 0; j < 4; j++) {
        int col = bn + wn * 64 + j * 16 + r;
        float b = bias[col];
        #pragma unroll
        for (int i = 0; i < 4; i++) {
            #pragma unroll
            for (int ii = 0; ii < 4; ii++) {
                int row = bm + wm * 64 + i * 16 + q * 4 + ii;
                if (row < M) {
                    float v = fmaxf(acc[i][j][ii] + b, 0.f);
                    if constexpr (BF16OUT)
                        ((ushort*)out)[(size_t)row * 256 + col] = (ushort)bf16u(v);
                    else
                        ((float*)out)[(size_t)row * 256 + col] = v;
                }
            }
        }
    }
}

// --------------------- fused pool + dense head + output ---------------------
// seg_ids are SORTED: graph gi owns contiguous node range found by binary
// search. Block gi: register-accumulate its rows (no atomics, no memset),
// then g2 = relu(g@Wd+bd) and out[gi] = g2@Wo+bo, all in one block.
__global__ __launch_bounds__(256) void pool_head(
    const float* __restrict__ h, const int* __restrict__ seg,
    const float* __restrict__ Wd, const float* __restrict__ bd,
    const float* __restrict__ Wo, const float* __restrict__ bo,
    float* __restrict__ out, int n)
{
    int gi = blockIdx.x;
    int j = threadIdx.x;

    int lo = 0, hi = n;
    while (lo < hi) { int m = (lo + hi) >> 1; if (seg[m] < gi) lo = m + 1; else hi = m; }
    int start = lo;
    hi = n;
    while (lo < hi) { int m = (lo + hi) >> 1; if (seg[m] < gi + 1) lo = m + 1; else hi = m; }
    int end = lo;

    float acc = 0.f;
    int nn = start;
    for (; nn + 4 <= end; nn += 4) {
        float t0 = h[(size_t)nn * 256 + j];
        float t1 = h[(size_t)(nn + 1) * 256 + j];
        float t2 = h[(size_t)(nn + 2) * 256 + j];
        float t3 = h[(size_t)(nn + 3) * 256 + j];
        acc += t0 + t1 + t2 + t3;
    }
    for (; nn < end; nn++) acc += h[(size_t)nn * 256 + j];

    __shared__ float gr[256];
    gr[j] = acc;
    __syncthreads();

    float a2 = bd[j];
    for (int k = 0; k < 256; k++)
        a2 += gr[k] * Wd[(size_t)k * 256 + j];
    a2 = fmaxf(a2, 0.f);

    float v = a2 * Wo[j];
    #pragma unroll
    for (int off = 32; off > 0; off >>= 1)
        v += __shfl_down(v, off, 64);
    __shared__ float partial[4];
    if ((j & 63) == 0) partial[j >> 6] = v;
    __syncthreads();
    if (j == 0)
        out[gi] = partial[0] + partial[1] + partial[2] + partial[3] + bo[0];
}

extern "C" void kernel_launch(void* const* d_in, const int* in_sizes, int n_in,
                              void* d_out, int out_size, void* d_ws, size_t ws_size,
                              hipStream_t stream) {
    const float* x   = (const float*)d_in[0];
    const int*   esrc= (const int*)  d_in[1];
    const int*   edst= (const int*)  d_in[2];
    const float* ew  = (const float*)d_in[3];
    const int*   seg = (const int*)  d_in[4];
    const float* W1  = (const float*)d_in[5];
    const float* b1  = (const float*)d_in[6];
    const float* W2  = (const float*)d_in[7];
    const float* b2  = (const float*)d_in[8];
    const float* Wd  = (const float*)d_in[9];
    const float* bd  = (const float*)d_in[10];
    const float* Wo  = (const float*)d_in[11];
    const float* bo  = (const float*)d_in[12];
    float* out = (float*)d_out;

    const int N = 50000, E = 800000, G = 128, H = 256, F = 128;
    const int NPAD = 50048;            // 391 * 128
    const int NB = (N + 255) / 256;    // 196

    // workspace; region0 reused: {xh, S1} early, h2 (fp32) late
    char* p = (char*)d_ws;
    char* region0 = p;                  p += (size_t)N * H * sizeof(float);    // 51.2 MB
    ushort* xh = (ushort*)region0;                                             // [N,128] bf16
    ushort* S1 = (ushort*)(region0 + (size_t)N * F * sizeof(ushort));          // [NPAD,128] bf16
    float*  h2 = (float*)region0;                                              // [N,256] f32
    ushort* h1 = (ushort*)p;            p += (size_t)N * H * sizeof(ushort);   // [N,256] bf16
    ushort* S2 = (ushort*)p;            p += (size_t)NPAD * H * sizeof(ushort);// [NPAD,256] bf16
    int*   deg = (int*)p;               p += (size_t)N * sizeof(int);
    int*   off = (int*)p;               p += (size_t)(N + 1) * sizeof(int) + 12;
    int*   cur = (int*)p;               p += (size_t)N * sizeof(int);
    int*   bsum= (int*)p;               p += 256 * sizeof(int);
    uint2* edges=(uint2*)p;             p += (size_t)E * sizeof(uint2);        // packed (src,w)
    ushort* Wt1= (ushort*)p;            p += (size_t)H * F * sizeof(ushort);   // [256,128]
    ushort* Wt2= (ushort*)p;            p += (size_t)H * H * sizeof(ushort);   // [256,256]

    // ---- CSR build + conversions ----
    hipMemsetAsync(deg, 0, (size_t)N * sizeof(int), stream);
    csr_hist<<<(E + 255) / 256, 256, 0, stream>>>(edst, deg, E);
    scan_block<<<NB, 256, 0, stream>>>(deg, off, bsum, N);
    scan_apply<<<NB, 256, 0, stream>>>(off, bsum, cur, N, E, NB);
    csr_fill<<<(E + 255) / 256, 256, 0, stream>>>(esrc, edst, ew, cur, edges, E);

    to_bf16_4<<<(N * F / 4 + 255) / 256, 256, 0, stream>>>(x, xh, N * F / 4);
    wtrans2<<<512, 256, 0, stream>>>(W1, Wt1, W2, Wt2);

    // ---- layer 1: S1 = A@x ; h1 = relu(S1@W1 + b1) ----
    spmm128<<<(N + 3) / 4, 256, 0, stream>>>(xh, off, edges, S1, N);
    gemm_tile<128, true><<<dim3(NPAD / 128, 2), 256, 0, stream>>>(S1, Wt1, b1, h1, N);

    // ---- layer 2: S2 = A@h1 ; h2 = relu(S2@W2 + b2) ----
    spmm256<<<(N + 3) / 4, 256, 0, stream>>>(h1, off, edges, S2, N);
    gemm_tile<256, false><<<dim3(NPAD / 128, 2), 256, 0, stream>>>(S2, Wt2, b2, h2, N);

    // ---- fused pool + head ----
    pool_head<<<G, 256, 0, stream>>>(h2, seg, Wd, bd, Wo, bo, out, N);
}